// Round 5
// baseline (77.939 us; speedup 1.0000x reference)
//
#include <hip/hip_runtime.h>
#include <math.h>

#define BB 256
#define NN 1024
#define KK 64
#define EE 128
#define TM 64   // rows per block in main kernel

typedef _Float16 half8 __attribute__((ext_vector_type(8)));
typedef float f32x4 __attribute__((ext_vector_type(4)));

// swizzled half-index for a [rows][128] f16 LDS tile: XOR 16B-slot bits by row&7
__device__ __forceinline__ int swz(int row, int halfcol) {
    return (row * EE + halfcol) ^ ((row & 7) << 3);
}

// async global->LDS 16B: linear LDS dest, per-lane global src
__device__ __forceinline__ void gload_lds16(const void* g, void* l) {
    __builtin_amdgcn_global_load_lds(
        (const __attribute__((address_space(1))) unsigned int*)g,
        (__attribute__((address_space(3))) unsigned int*)l, 16, 0, 0);
}

// ---------------- prep: per-batch combined matrix Mt (f16), bias; + W2 -> f16 ----------------
// C = adj @ (w_real + i w_imag); M = [[Cr, Ci], [-Ci, Cr]]; x_pre = [cos|sin] @ M + [br|bi]
// Mt[f][j] = M[j][f]  (MFMA B-frags = contiguous rows)
__global__ __launch_bounds__(256) void prep_kernel(
    const float* __restrict__ recip,
    const int* __restrict__ space_group,
    const float* __restrict__ graphs,
    const float* __restrict__ w_real,
    const float* __restrict__ w_imag,
    const float* __restrict__ b_real,
    const float* __restrict__ b_imag,
    const float* __restrict__ W2,
    _Float16* __restrict__ Mt,
    float* __restrict__ bbout,
    _Float16* __restrict__ W2h)
{
    const int b = blockIdx.x;
    const int t = threadIdx.x;
    const int sg = space_group[b] - 1;

    if (b < EE * EE / 256) {
        const int idx = b * 256 + t;
        W2h[idx] = (_Float16)W2[idx];
    }

    __shared__ float adjL[KK * KK];
    __shared__ float wrL[KK * KK];
    __shared__ float wiL[KK * KK];

    const float* adjG = graphs + (size_t)sg * KK * KK;
    const float* wrG  = w_real + (size_t)sg * KK * KK;
    const float* wiG  = w_imag + (size_t)sg * KK * KK;
    for (int idx = t; idx < KK * KK; idx += 256) {
        adjL[idx] = adjG[idx];
        wrL[idx]  = wrG[idx];
        wiL[idx]  = wiG[idx];
    }
    __syncthreads();

    const int i  = t >> 2;
    const int f0 = (t & 3) * 16;
    float cr[16], ci[16];
#pragma unroll
    for (int c = 0; c < 16; ++c) { cr[c] = 0.f; ci[c] = 0.f; }
    for (int k = 0; k < KK; ++k) {
        const float a = adjL[i * KK + k];
#pragma unroll
        for (int c = 0; c < 16; ++c) {
            cr[c] += a * wrL[k * KK + f0 + c];
            ci[c] += a * wiL[k * KK + f0 + c];
        }
    }
    _Float16* Mb = Mt + (size_t)b * EE * EE;
#pragma unroll
    for (int c = 0; c < 16; ++c) {
        const int f = f0 + c;
        Mb[f * EE + i]             = (_Float16)cr[c];
        Mb[f * EE + KK + i]        = (_Float16)(-ci[c]);
        Mb[(KK + f) * EE + i]      = (_Float16)ci[c];
        Mb[(KK + f) * EE + KK + i] = (_Float16)cr[c];
    }
    if (t < EE) {
        bbout[b * EE + t] = (t < KK) ? b_real[sg * KK + t] : b_imag[sg * KK + (t - KK)];
    }
}

// ---------------- main fused MFMA kernel (2x2 wave tiling) ----------------
// wave w = (wr,wc): rows wr*32+[0,32) (2 row-tiles), cols wc*64+[0,64) (4 col-tiles)
__global__ __launch_bounds__(256) void main_kernel(
    const float* __restrict__ pos,      // B*N*3
    const float* __restrict__ recip,    // B*9
    const float* __restrict__ abc,      // K*3
    const _Float16* __restrict__ Mt,    // B*E*E f16
    const float* __restrict__ bball,    // B*E
    const _Float16* __restrict__ W2h,   // E*E f16
    const float* __restrict__ b2,       // E
    const float* __restrict__ gamma,    // E
    const float* __restrict__ beta,     // E
    float* __restrict__ out)            // B*N*E
{
    const int d = blockIdx.x;
    // XCD swizzle: all 16 blocks of a batch on one XCD (Mt fetched once per XCD L2)
    const int j  = d >> 3;
    const int b  = (d & 7) * 32 + (j >> 4);
    const int n0 = (j & 15) * TM;
    const int t  = threadIdx.x;
    const int w    = t >> 6;
    const int wr   = w >> 1;                // 0..1 row half
    const int wc   = w & 1;                 // 0..1 col half
    const int lane = t & 63;
    const int ln15 = lane & 15;
    const int kg   = lane >> 4;             // 0..3

    __shared__ __align__(16) _Float16 Bt[EE * EE];  // 32KB: Mt, later W2h
    __shared__ __align__(16) _Float16 X[TM * EE];   // 16KB: silu output
    __shared__ float abcL[KK * 3];
    __shared__ float2 pbuf[TM][2];                  // LN partials per row, per col-half

    if (t < KK * 3) abcL[t] = abc[t];
    __syncthreads();   // abcL visible (before big loads are outstanding)

    // ---- issue async Mt staging: LDS linear, global source inverse-swizzled ----
    {
        const char* src = (const char*)(Mt + (size_t)b * EE * EE);
#pragma unroll
        for (int i = 0; i < 8; ++i) {
            const int c16 = t + i * 256;
            const int row = c16 >> 4;
            const int sl  = c16 & 15;
            const int g   = row * 16 + (sl ^ (row & 7));
            gload_lds16(src + g * 16, (char*)Bt + c16 * 16);
        }
    }

    // ---- per-lane A-fragments via sincos, for BOTH row-tiles (hides Mt load) ----
    // A layout per tile: row=lane&15, k=(lane>>4)*8+j
    half8 afrag[2][4];
#pragma unroll
    for (int rt = 0; rt < 2; ++rt) {
        const int grow = n0 + wr * 32 + rt * 16 + ln15;
        const float* pr = pos + ((size_t)b * NN + grow) * 3;
        const float px = pr[0], py = pr[1], pz = pr[2];
        const float* R = recip + b * 9;
        const float u0 = px * R[0] + py * R[3] + pz * R[6];
        const float u1 = px * R[1] + py * R[4] + pz * R[7];
        const float u2 = px * R[2] + py * R[5] + pz * R[8];
#pragma unroll
        for (int mq = 0; mq < 2; ++mq) {
            _Float16 cb[8], sb[8];
#pragma unroll
            for (int jj = 0; jj < 8; ++jj) {
                const int k = mq * 32 + kg * 8 + jj;
                const float ph = 6.28318530717958647692f *
                    (u0 * abcL[k * 3 + 0] + u1 * abcL[k * 3 + 1] + u2 * abcL[k * 3 + 2]);
                float s, c;
                __sincosf(ph, &s, &c);
                cb[jj] = (_Float16)c;
                sb[jj] = (_Float16)s;
            }
            afrag[rt][mq]     = *(half8*)cb;   // cos -> k-chunks 0,1
            afrag[rt][mq + 2] = *(half8*)sb;   // sin -> k-chunks 2,3
        }
    }
    __syncthreads();   // drains vmcnt(0): Bt(Mt) ready

    // ---- matmul1: x_pre = A @ M (each col-tile's B-frag loaded once, used by 2 row-tiles) ----
    f32x4 acc[2][4];
#pragma unroll
    for (int rt = 0; rt < 2; ++rt)
#pragma unroll
        for (int ct = 0; ct < 4; ++ct) acc[rt][ct] = (f32x4){0.f, 0.f, 0.f, 0.f};

#pragma unroll
    for (int ct = 0; ct < 4; ++ct) {
        const int n = wc * 64 + ct * 16 + ln15;
#pragma unroll
        for (int kc = 0; kc < 4; ++kc) {
            const half8 bf = *(const half8*)&Bt[swz(n, kc * 32 + kg * 8)];
            acc[0][ct] = __builtin_amdgcn_mfma_f32_16x16x32_f16(afrag[0][kc], bf, acc[0][ct], 0, 0, 0);
            acc[1][ct] = __builtin_amdgcn_mfma_f32_16x16x32_f16(afrag[1][kc], bf, acc[1][ct], 0, 0, 0);
        }
    }

    // ---- bias + silu -> X (D layout: row=(lane>>4)*4+r2, col=lane&15) ----
#pragma unroll
    for (int ct = 0; ct < 4; ++ct) {
        const int col = wc * 64 + ct * 16 + ln15;
        const float bbv = bball[b * EE + col];
#pragma unroll
        for (int rt = 0; rt < 2; ++rt) {
#pragma unroll
            for (int r2 = 0; r2 < 4; ++r2) {
                const float v = acc[rt][ct][r2] + bbv;
                const int rr = wr * 32 + rt * 16 + kg * 4 + r2;
                X[swz(rr, col)] = (_Float16)(v / (1.f + __expf(-v)));
            }
        }
    }
    __syncthreads();   // X visible; all waves done reading Bt(Mt)

    // ---- issue async W2 staging into Bt ----
    {
        const char* src = (const char*)W2h;
#pragma unroll
        for (int i = 0; i < 8; ++i) {
            const int c16 = t + i * 256;
            const int row = c16 >> 4;
            const int sl  = c16 & 15;
            const int g   = row * 16 + (sl ^ (row & 7));
            gload_lds16(src + g * 16, (char*)Bt + c16 * 16);
        }
    }

    // ---- A-frags for matmul2 from X (hides part of W2 load) ----
    half8 a2[2][4];
#pragma unroll
    for (int rt = 0; rt < 2; ++rt)
#pragma unroll
        for (int kc = 0; kc < 4; ++kc)
            a2[rt][kc] = *(const half8*)&X[swz(wr * 32 + rt * 16 + ln15, kc * 32 + kg * 8)];
    __syncthreads();   // drains vmcnt(0): Bt(W2) ready

    // ---- matmul2: y = X @ W2^T ----
    f32x4 acc2[2][4];
#pragma unroll
    for (int rt = 0; rt < 2; ++rt)
#pragma unroll
        for (int ct = 0; ct < 4; ++ct) acc2[rt][ct] = (f32x4){0.f, 0.f, 0.f, 0.f};

#pragma unroll
    for (int ct = 0; ct < 4; ++ct) {
        const int n = wc * 64 + ct * 16 + ln15;
#pragma unroll
        for (int kc = 0; kc < 4; ++kc) {
            const half8 bf = *(const half8*)&Bt[swz(n, kc * 32 + kg * 8)];
            acc2[0][ct] = __builtin_amdgcn_mfma_f32_16x16x32_f16(a2[0][kc], bf, acc2[0][ct], 0, 0, 0);
            acc2[1][ct] = __builtin_amdgcn_mfma_f32_16x16x32_f16(a2[1][kc], bf, acc2[1][ct], 0, 0, 0);
        }
    }

    // ---- + b2; LN partials over this wave's 64-col half ----
#pragma unroll
    for (int ct = 0; ct < 4; ++ct) {
        const int col = wc * 64 + ct * 16 + ln15;
        const float b2v = b2[col];
#pragma unroll
        for (int rt = 0; rt < 2; ++rt)
#pragma unroll
            for (int r2 = 0; r2 < 4; ++r2) acc2[rt][ct][r2] += b2v;
    }
    float ps[2][4], pq[2][4];
#pragma unroll
    for (int rt = 0; rt < 2; ++rt) {
#pragma unroll
        for (int r2 = 0; r2 < 4; ++r2) {
            float s = 0.f, q = 0.f;
#pragma unroll
            for (int ct = 0; ct < 4; ++ct) {
                const float v = acc2[rt][ct][r2];
                s += v; q += v * v;
            }
#pragma unroll
            for (int m = 1; m < 16; m <<= 1) {
                s += __shfl_xor(s, m);
                q += __shfl_xor(q, m);
            }
            ps[rt][r2] = s; pq[rt][r2] = q;
        }
    }
    if (ln15 == 0) {
#pragma unroll
        for (int rt = 0; rt < 2; ++rt)
#pragma unroll
            for (int r2 = 0; r2 < 4; ++r2) {
                const int rr = wr * 32 + rt * 16 + kg * 4 + r2;
                pbuf[rr][wc] = make_float2(ps[rt][r2], pq[rt][r2]);
            }
    }
    __syncthreads();

    // ---- combine halves, normalize, store ----
    const float inv = 1.f / EE;
    float mu[2][4], rs[2][4];
#pragma unroll
    for (int rt = 0; rt < 2; ++rt) {
#pragma unroll
        for (int r2 = 0; r2 < 4; ++r2) {
            const int rr = wr * 32 + rt * 16 + kg * 4 + r2;
            const float2 pa = pbuf[rr][0];
            const float2 pb = pbuf[rr][1];
            const float s = pa.x + pb.x;
            const float q = pa.y + pb.y;
            const float m = s * inv;
            mu[rt][r2] = m;
            rs[rt][r2] = rsqrtf(fmaxf(q * inv - m * m, 0.f) + 1e-5f);
        }
    }
#pragma unroll
    for (int ct = 0; ct < 4; ++ct) {
        const int col = wc * 64 + ct * 16 + ln15;
        const float g  = gamma[col];
        const float be = beta[col];
#pragma unroll
        for (int rt = 0; rt < 2; ++rt) {
#pragma unroll
            for (int r2 = 0; r2 < 4; ++r2) {
                const int rr = wr * 32 + rt * 16 + kg * 4 + r2;
                out[((size_t)b * NN + n0 + rr) * EE + col] =
                    (acc2[rt][ct][r2] - mu[rt][r2]) * rs[rt][r2] * g + be;
            }
        }
    }
}

extern "C" void kernel_launch(void* const* d_in, const int* in_sizes, int n_in,
                              void* d_out, int out_size, void* d_ws, size_t ws_size,
                              hipStream_t stream) {
    const float* pos    = (const float*)d_in[0];
    const float* recip  = (const float*)d_in[1];
    const int*   sgp    = (const int*)d_in[2];
    const float* abc    = (const float*)d_in[3];
    const float* graphs = (const float*)d_in[4];
    const float* wr     = (const float*)d_in[5];
    const float* wi     = (const float*)d_in[6];
    const float* br     = (const float*)d_in[7];
    const float* bi     = (const float*)d_in[8];
    const float* W2     = (const float*)d_in[9];
    const float* b2     = (const float*)d_in[10];
    const float* gm     = (const float*)d_in[11];
    const float* bt     = (const float*)d_in[12];
    float* out = (float*)d_out;

    char* ws = (char*)d_ws;
    _Float16* Mt    = (_Float16*)ws;                                    // B*E*E f16 = 8 MiB
    _Float16* W2h   = (_Float16*)(ws + (size_t)BB * EE * EE * 2);       // E*E f16 = 32 KiB
    float*    bball = (float*)(ws + (size_t)BB * EE * EE * 2 + 32768);  // B*E f32

    hipLaunchKernelGGL(prep_kernel, dim3(BB), dim3(256), 0, stream,
                       recip, sgp, graphs, wr, wi, br, bi, W2, Mt, bball, W2h);
    hipLaunchKernelGGL(main_kernel, dim3(BB * NN / TM), dim3(256), 0, stream,
                       pos, recip, abc, Mt, bball, W2h, b2, gm, bt, out);
}